// Round 2
// baseline (2705.619 us; speedup 1.0000x reference)
//
#include <hip/hip_runtime.h>
#include <math.h>

typedef __bf16 bf16;
typedef __bf16 bf16x8 __attribute__((ext_vector_type(8)));
typedef float f32x4 __attribute__((ext_vector_type(4)));

#define MFMA_B16(a,b,c) __builtin_amdgcn_mfma_f32_16x16x32_bf16((a),(b),(c),0,0,0)

constexpr int TMAXc = 30;
constexpr int Bc = 128, Pc = 196, Fc = 2048, Ec = 512, Hc = 1024, Vc = 10000;
constexpr int G4c = 4 * Hc;          // 4096
constexpr int NSTEP = TMAXc + 1;     // 31
constexpr int MALLc = NSTEP * Bc;    // 3968
constexpr int MOUTc = TMAXc * Bc;    // 3840
constexpr int NBLK = 256;            // persistent kernel grid

__device__ __forceinline__ float sigm(float x){ return 1.0f/(1.0f+expf(-x)); }

__device__ __forceinline__ void gll16(const void* g, void* l){
  __builtin_amdgcn_global_load_lds((const __attribute__((address_space(1))) void*)g,
                                   (__attribute__((address_space(3))) void*)l, 16, 0, 0);
}

// ---------------- prep kernels ----------------

__global__ void mean_kernel(const float* __restrict__ enc, bf16* __restrict__ feat){
  int idx = blockIdx.x*256 + threadIdx.x;
  if (idx >= Bc*Fc) return;
  int b = idx >> 11, f = idx & (Fc-1);
  const float* p = enc + (size_t)b*Pc*Fc + f;
  float s = 0.f;
  for (int q = 0; q < Pc; ++q) s += p[(size_t)q*Fc];
  feat[idx] = (bf16)(s * (1.0f/(float)Pc));
}

__global__ void conv_kernel(const float* __restrict__ src, bf16* __restrict__ dst, int n){
  int i = blockIdx.x*256 + threadIdx.x;
  if (i < n) dst[i] = (bf16)src[i];
}

// W_ih (4096,512) -> permuted rows: row' = j*4+g  <-  row g*1024+j ; plain bf16
__global__ void permconv_ih(const float* __restrict__ W, bf16* __restrict__ Wp){
  int i = blockIdx.x*256 + threadIdx.x;
  if (i >= G4c*Ec) return;
  int rp = i >> 9, k = i & 511;
  int g = rp & 3, j = rp >> 2;
  Wp[i] = (bf16)W[(size_t)(g*Hc + j)*Ec + k];
}

// W_hh (4096,1024) -> permuted + split hi/lo
__global__ void permsplit_hh(const float* __restrict__ W, bf16* __restrict__ Whi, bf16* __restrict__ Wlo){
  int i = blockIdx.x*256 + threadIdx.x;
  if (i >= G4c*Hc) return;
  int rp = i >> 10, k = i & 1023;
  int g = rp & 3, j = rp >> 2;
  float v = W[(size_t)(g*Hc + j)*Hc + k];
  bf16 h = (bf16)v;
  Whi[i] = h; Wlo[i] = (bf16)(v - (float)h);
}

__global__ void split_kernel(const float* __restrict__ W, bf16* __restrict__ Whi, bf16* __restrict__ Wlo, int n){
  int i = blockIdx.x*256 + threadIdx.x;
  if (i >= n) return;
  float v = W[i]; bf16 h = (bf16)v;
  Whi[i] = h; Wlo[i] = (bf16)(v - (float)h);
}

__global__ void bcomb_kernel(const float* __restrict__ bih, const float* __restrict__ bhh, float* __restrict__ bc){
  int i = blockIdx.x*256 + threadIdx.x;
  if (i >= G4c) return;
  int g = i & 3, j = i >> 2;
  bc[i] = bih[g*Hc + j] + bhh[g*Hc + j];
}

// embedding gather into X_all rows 128..3967 (row = s*128+b holds x_s = emb_{s-1})
__global__ void gather_kernel(const float* __restrict__ emb, const int* __restrict__ gt, bf16* __restrict__ X){
  int idx = blockIdx.x*256 + threadIdx.x;
  if (idx >= MOUTc*(Ec/4)) return;
  int r = idx >> 7, ei = (idx & 127) * 4;
  int s = (r >> 7) + 1, b = r & 127;
  int tok = gt[b*(TMAXc+1) + (s-1)];
  const float* src = emb + (size_t)tok*Ec + ei;
  bf16* dst = X + (size_t)(s*Bc + b)*Ec + ei;
  dst[0]=(bf16)src[0]; dst[1]=(bf16)src[1]; dst[2]=(bf16)src[2]; dst[3]=(bf16)src[3];
}

// ---------------- generic MFMA GEMM (m97 structure, 128x128 tile, BK=32) ----------------
// C[m,n] = sum_k A[m,k]*B[n,k]  (B is N x K row-major). EPI: 0=x0(sig+BN), 1=Xg(bias), 2=FC(bias+mask)
template<int EPI, bool SPLIT>
__global__ __launch_bounds__(256, 2) void gemm_kernel(
  const bf16* __restrict__ Ahi, const bf16* __restrict__ Alo,
  const bf16* __restrict__ Bhi, const bf16* __restrict__ Blo,
  int M, int N, int K, int ntiles,
  const float* __restrict__ p0, const float* __restrict__ p1, const float* __restrict__ p2,
  bf16* __restrict__ outb, float* __restrict__ outf, const int* __restrict__ lens)
{
  constexpr int BK = 32;
  __shared__ alignas(16) bf16 sAh[128*BK], sBh[128*BK];
  __shared__ alignas(16) bf16 sAl[SPLIT ? 128*BK : 8], sBl[SPLIT ? 128*BK : 8];

  int tid = threadIdx.x;
  int lane = tid & 63, w = tid >> 6, wr = w >> 1, wc = w & 1;
  int bid = blockIdx.x;
  int mt = bid / ntiles, nt = bid - mt*ntiles;
  int m0 = mt*128, n0 = nt*128;

  f32x4 acc[4][4] = {};

  for (int kt = 0; kt < K; kt += BK) {
    #pragma unroll
    for (int is = 0; is < 2; ++is) {
      int p = tid*16 + is*4096;          // byte offset in 8KB tile
      int r = p >> 6, c = (p & 63) >> 1; // row, elem-col
      int ldsoff = w*512 + is*2048;      // elems (wave-uniform base)
      gll16(Ahi + (size_t)(m0 + r)*K + kt + c, &sAh[ldsoff]);
      int rb = n0 + r; rb = rb < N ? rb : N - 1;
      gll16(Bhi + (size_t)rb*K + kt + c, &sBh[ldsoff]);
      if constexpr (SPLIT) {
        gll16(Alo + (size_t)(m0 + r)*K + kt + c, &sAl[ldsoff]);
        gll16(Blo + (size_t)rb*K + kt + c, &sBl[ldsoff]);
      }
    }
    __syncthreads();

    int koff = (lane >> 4) * 8;
    bf16x8 ah[4], bh[4], al[SPLIT?4:1], bl[SPLIT?4:1];
    #pragma unroll
    for (int mi = 0; mi < 4; ++mi) {
      int rr = wr*64 + mi*16 + (lane & 15);
      ah[mi] = *(const bf16x8*)&sAh[rr*BK + koff];
      if constexpr (SPLIT) al[mi] = *(const bf16x8*)&sAl[rr*BK + koff];
    }
    #pragma unroll
    for (int ni = 0; ni < 4; ++ni) {
      int rr = wc*64 + ni*16 + (lane & 15);
      bh[ni] = *(const bf16x8*)&sBh[rr*BK + koff];
      if constexpr (SPLIT) bl[ni] = *(const bf16x8*)&sBl[rr*BK + koff];
    }
    #pragma unroll
    for (int mi = 0; mi < 4; ++mi)
      #pragma unroll
      for (int ni = 0; ni < 4; ++ni) {
        acc[mi][ni] = MFMA_B16(ah[mi], bh[ni], acc[mi][ni]);
        if constexpr (SPLIT) {
          acc[mi][ni] = MFMA_B16(ah[mi], bl[ni], acc[mi][ni]);
          acc[mi][ni] = MFMA_B16(al[mi], bh[ni], acc[mi][ni]);
        }
      }
    __syncthreads();
  }

  const float rbn = rsqrtf(1.0f + 1e-5f);
  #pragma unroll
  for (int mi = 0; mi < 4; ++mi) {
    #pragma unroll
    for (int ni = 0; ni < 4; ++ni) {
      int row = m0 + wr*64 + mi*16 + ((lane >> 4) << 2);
      int col = n0 + wc*64 + ni*16 + (lane & 15);
      #pragma unroll
      for (int j = 0; j < 4; ++j) {
        int rr = row + j;
        float v = acc[mi][ni][j];
        if constexpr (EPI == 0) {
          v = sigm(v + p0[col]);
          v = p1[col]*(v*rbn) + p2[col];
          outb[(size_t)rr*Ec + col] = (bf16)v;
        } else if constexpr (EPI == 1) {
          outb[(size_t)rr*G4c + col] = (bf16)(v + p0[col]);
        } else {
          if (col < N) {
            v += p0[col];
            int t = rr >> 7, b = rr & 127;
            float o = (t < (lens[b] - 1)) ? v : 0.0f;
            outf[(size_t)b*(TMAXc*Vc) + (size_t)t*Vc + col] = o;
          }
        }
      }
    }
  }
}

// ---------------- persistent LSTM recurrence ----------------
// 256 blocks x 256 threads, 1 block/CU (128 KB LDS). Block (strip,rh):
// strip owns pcols [strip*32, strip*32+32), rh owns rows [rh*64, rh*64+64).
// W_hh hi/lo slice lives in LDS (XOR-swizzled) for all 31 steps.
// h fragments read straight from global (L2-resident). One grid barrier/step.

__device__ __forceinline__ void gridbar(int* flags, int target){
  __threadfence();                 // release this thread's h/c stores
  __syncthreads();                 // all block stores+fences done
  if (threadIdx.x == 0)
    __hip_atomic_store(&flags[blockIdx.x], target, __ATOMIC_RELEASE, __HIP_MEMORY_SCOPE_AGENT);
  while (__hip_atomic_load(&flags[threadIdx.x], __ATOMIC_ACQUIRE, __HIP_MEMORY_SCOPE_AGENT) < target)
    __builtin_amdgcn_s_sleep(2);
  __syncthreads();
  __threadfence();                 // invalidate caches before reading fresh h
}

__global__ __launch_bounds__(256, 1) void lstm_persist(
  const bf16* __restrict__ Whi, const bf16* __restrict__ Wlo, // [4096][1024] permuted
  const bf16* __restrict__ Xg,                                 // [31*128][4096]
  bf16* hAh, bf16* hAl, bf16* hBh, bf16* hBl,                  // [128][1024] ping-pong
  float* __restrict__ cst,                                     // [128][1024]
  bf16* __restrict__ Hh, bf16* __restrict__ Hl,                // [3840][1024]
  int* __restrict__ flags)
{
  extern __shared__ char sWc[];    // 128 KB: hi at 0, lo at +65536, swizzled
  int tid = threadIdx.x, lane = tid & 63, w = tid >> 6;
  int bid = blockIdx.x;
  int strip = bid >> 1, rh = bid & 1;
  int pc0 = strip * 32;
  int row0 = rh * 64 + w * 16;

  // ---- fill W slice into LDS (one-time), swizzle byte ^= (p&7)<<4 ----
  for (int ch = tid; ch < 4096; ch += 256) {
    int p = ch >> 7;             // 0..31
    int k = (ch & 127) * 8;      // 0..1016
    bf16x8 vh = *(const bf16x8*)&Whi[(size_t)(pc0 + p)*Hc + k];
    bf16x8 vl = *(const bf16x8*)&Wlo[(size_t)(pc0 + p)*Hc + k];
    int be = (p*Hc + k)*2;
    int sw = (p & 7) << 4;
    *(bf16x8*)(sWc + (be ^ sw)) = vh;
    *(bf16x8*)(sWc + ((be + 65536) ^ sw)) = vl;
  }
  __syncthreads();

  int bp = lane & 15;            // B-frag col within frag
  int bk = (lane >> 4) << 3;     // B-frag k offset
  int bswz = (bp & 7) << 4;
  int rbase = row0 + ((lane >> 4) << 2);

  const bf16 *hrh = hAh, *hrl = hAl;
  bf16 *hwh = hBh, *hwl = hBl;

  #pragma unroll 1
  for (int s = 0; s < NSTEP; ++s) {
    // acc chains: HH init from Xg, HL/LH zero (6 independent MFMA chains)
    f32x4 aHH[2], aHL[2], aLH[2];
    float cpre[2][4];
    #pragma unroll
    for (int ni = 0; ni < 2; ++ni) {
      int pcol = pc0 + ni*16 + bp;
      int hcol = pcol >> 2;
      #pragma unroll
      for (int j = 0; j < 4; ++j) {
        aHH[ni][j] = (float)Xg[(size_t)(s*Bc + rbase + j)*G4c + pcol];
        cpre[ni][j] = cst[(size_t)(rbase + j)*Hc + hcol];
      }
      aHL[ni] = (f32x4){0.f,0.f,0.f,0.f};
      aLH[ni] = (f32x4){0.f,0.f,0.f,0.f};
    }

    const bf16* pah = hrh + (size_t)(row0 + bp)*Hc + bk;
    const bf16* pal = hrl + (size_t)(row0 + bp)*Hc + bk;

    #pragma unroll
    for (int ks = 0; ks < 32; ++ks) {
      bf16x8 avh = *(const bf16x8*)(pah + ks*32);
      bf16x8 avl = *(const bf16x8*)(pal + ks*32);
      #pragma unroll
      for (int ni = 0; ni < 2; ++ni) {
        int be = ((ni*16 + bp)*Hc + ks*32 + bk)*2;
        bf16x8 bvh = *(const bf16x8*)(sWc + (be ^ bswz));
        bf16x8 bvl = *(const bf16x8*)(sWc + ((be + 65536) ^ bswz));
        aHH[ni] = MFMA_B16(avh, bvh, aHH[ni]);
        aHL[ni] = MFMA_B16(avh, bvl, aHL[ni]);
        aLH[ni] = MFMA_B16(avl, bvh, aLH[ni]);
      }
    }

    // ---- LSTM epilogue: combine 4 gates across lane-quads ----
    int e = lane & 3;
    #pragma unroll
    for (int ni = 0; ni < 2; ++ni) {
      int pcol = pc0 + ni*16 + bp;
      int hcol = pcol >> 2;
      #pragma unroll
      for (int j = 0; j < 4; ++j) {
        int rr = rbase + j;
        float v = aHH[ni][j] + aHL[ni][j] + aLH[ni][j];
        float a  = v;
        float b1 = __shfl_xor(v, 1);
        float c2 = __shfl_xor(v, 2);
        float d3 = __shfl_xor(v, 3);
        int m;
        m = e;     float gI = (m==0)?a:(m==1)?b1:(m==2)?c2:d3;
        m = e ^ 1; float gF = (m==0)?a:(m==1)?b1:(m==2)?c2:d3;
        m = e ^ 2; float gG = (m==0)?a:(m==1)?b1:(m==2)?c2:d3;
        m = e ^ 3; float gO = (m==0)?a:(m==1)?b1:(m==2)?c2:d3;

        size_t oi = (size_t)rr*Hc + hcol;
        float co = cpre[ni][j];
        float cn = sigm(gF)*co + sigm(gI)*tanhf(gG);
        float hn = sigm(gO)*tanhf(cn);
        bf16 hhi = (bf16)hn;
        bf16 hlo = (bf16)(hn - (float)hhi);
        if (e == 0) cst[oi] = cn;
        else if (e == 1) hwh[oi] = hhi;
        else if (e == 2) hwl[oi] = hlo;
        else if (s > 0) {
          size_t ho = (size_t)((s-1)*Bc + rr)*Hc + hcol;
          Hh[ho] = hhi; Hl[ho] = hlo;
        }
      }
    }

    // swap ping-pong
    const bf16* t0 = hrh; hrh = hwh; hwh = (bf16*)t0;
    const bf16* t1 = hrl; hrl = hwl; hwl = (bf16*)t1;

    if (s < NSTEP - 1) gridbar(flags, s + 1);
  }
}

// ---------------- launch ----------------

extern "C" void kernel_launch(void* const* d_in, const int* in_sizes, int n_in,
                              void* d_out, int out_size, void* d_ws, size_t ws_size,
                              hipStream_t stream)
{
  const float* enc   = (const float*)d_in[0];
  const int*   gt    = (const int*)  d_in[1];
  const int*   lens  = (const int*)  d_in[2];
  const float* emb   = (const float*)d_in[3];
  const float* Winit = (const float*)d_in[4];
  const float* binit = (const float*)d_in[5];
  const float* gam   = (const float*)d_in[6];
  const float* bet   = (const float*)d_in[7];
  const float* Wih   = (const float*)d_in[8];
  const float* bih   = (const float*)d_in[9];
  const float* Whh   = (const float*)d_in[10];
  const float* bhh   = (const float*)d_in[11];
  const float* Wfc   = (const float*)d_in[12];
  const float* bfc   = (const float*)d_in[13];
  float* out = (float*)d_out;

  char* ws = (char*)d_ws;
  size_t off = 0;
  auto alloc = [&](size_t bytes) -> char* {
    char* p = ws + off;
    off += (bytes + 255) & ~(size_t)255;
    return p;
  };

  bf16* featB  = (bf16*)alloc((size_t)Bc*Fc*2);
  bf16* WinitB = (bf16*)alloc((size_t)Ec*Fc*2);
  bf16* WihpB  = (bf16*)alloc((size_t)G4c*Ec*2);
  bf16* WhhHi  = (bf16*)alloc((size_t)G4c*Hc*2);
  bf16* WhhLo  = (bf16*)alloc((size_t)G4c*Hc*2);
  bf16* WfcHi  = (bf16*)alloc((size_t)Vc*Hc*2);
  bf16* WfcLo  = (bf16*)alloc((size_t)Vc*Hc*2);
  float* bcomb = (float*)alloc((size_t)G4c*4);
  bf16* Xall   = (bf16*)alloc((size_t)MALLc*Ec*2);
  bf16* Xg     = (bf16*)alloc((size_t)MALLc*G4c*2);
  bf16* h0h    = (bf16*)alloc((size_t)Bc*Hc*2);
  bf16* h0l    = (bf16*)alloc((size_t)Bc*Hc*2);
  bf16* h1h    = (bf16*)alloc((size_t)Bc*Hc*2);
  bf16* h1l    = (bf16*)alloc((size_t)Bc*Hc*2);
  float* cst   = (float*)alloc((size_t)Bc*Hc*4);
  bf16* HallH  = (bf16*)alloc((size_t)MOUTc*Hc*2);
  bf16* HallL  = (bf16*)alloc((size_t)MOUTc*Hc*2);
  int*  flags  = (int*) alloc((size_t)NBLK*4);

  if (off > ws_size) return;

  // zero initial state + barrier flags (captured in graph -> re-done every replay)
  hipMemsetAsync(h0h, 0, (size_t)Bc*Hc*2, stream);
  hipMemsetAsync(h0l, 0, (size_t)Bc*Hc*2, stream);
  hipMemsetAsync(cst, 0, (size_t)Bc*Hc*4, stream);
  hipMemsetAsync(flags, 0, (size_t)NBLK*4, stream);

  // prep
  mean_kernel<<<(Bc*Fc + 255)/256, 256, 0, stream>>>(enc, featB);
  conv_kernel<<<((Ec*Fc) + 255)/256, 256, 0, stream>>>(Winit, WinitB, Ec*Fc);
  permconv_ih<<<((G4c*Ec) + 255)/256, 256, 0, stream>>>(Wih, WihpB);
  permsplit_hh<<<((G4c*Hc) + 255)/256, 256, 0, stream>>>(Whh, WhhHi, WhhLo);
  split_kernel<<<((Vc*Hc) + 255)/256, 256, 0, stream>>>(Wfc, WfcHi, WfcLo, Vc*Hc);
  bcomb_kernel<<<(G4c + 255)/256, 256, 0, stream>>>(bih, bhh, bcomb);
  gather_kernel<<<((MOUTc*(Ec/4)) + 255)/256, 256, 0, stream>>>(emb, gt, Xall);

  // GEMM A: x0 = sigmoid(feat @ Winit^T + b) * BN -> X_all rows 0..127
  gemm_kernel<0,false><<<1*4, 256, 0, stream>>>(
      featB, nullptr, WinitB, nullptr, Bc, Ec, Fc, 4,
      binit, gam, bet, Xall, nullptr, nullptr);

  // GEMM C: Xg = X_all @ Wihp^T + bcomb   (3968 x 4096, K=512)
  gemm_kernel<1,false><<<31*32, 256, 0, stream>>>(
      Xall, nullptr, WihpB, nullptr, MALLc, G4c, Ec, 32,
      bcomb, nullptr, nullptr, Xg, nullptr, nullptr);

  // recurrence: one persistent kernel, 31 steps, hand-rolled grid barrier
  hipFuncSetAttribute(reinterpret_cast<const void*>(lstm_persist),
                      hipFuncAttributeMaxDynamicSharedMemorySize, 131072);
  lstm_persist<<<NBLK, 256, 131072, stream>>>(
      WhhHi, WhhLo, Xg, h0h, h0l, h1h, h1l, cst, HallH, HallL, flags);

  // GEMM E: preds = Hall @ Wfc^T + b_fc, masked -> out (split-3)
  gemm_kernel<2,true><<<30*79, 256, 0, stream>>>(
      HallH, HallL, WfcHi, WfcLo, MOUTc, Vc, Hc, 79,
      bfc, nullptr, nullptr, nullptr, out, lens);
}

// Round 3
// 1299.166 us; speedup vs baseline: 2.0826x; 2.0826x over previous
//
#include <hip/hip_runtime.h>
#include <math.h>

typedef __bf16 bf16;
typedef __bf16 bf16x8 __attribute__((ext_vector_type(8)));
typedef float f32x4 __attribute__((ext_vector_type(4)));

#define MFMA_B16(a,b,c) __builtin_amdgcn_mfma_f32_16x16x32_bf16((a),(b),(c),0,0,0)

constexpr int TMAXc = 30;
constexpr int Bc = 128, Pc = 196, Fc = 2048, Ec = 512, Hc = 1024, Vc = 10000;
constexpr int G4c = 4 * Hc;          // 4096
constexpr int NSTEP = TMAXc + 1;     // 31
constexpr int MALLc = NSTEP * Bc;    // 3968
constexpr int MOUTc = TMAXc * Bc;    // 3840
constexpr int NBLK = 256;            // persistent kernel grid

__device__ __forceinline__ float fsigm(float x){
  return __fdividef(1.0f, 1.0f + __expf(-x));
}
__device__ __forceinline__ float ftanh(float x){
  return 1.0f - __fdividef(2.0f, __expf(2.0f*x) + 1.0f);
}

__device__ __forceinline__ void gll16(const void* g, void* l){
  __builtin_amdgcn_global_load_lds((const __attribute__((address_space(1))) void*)g,
                                   (__attribute__((address_space(3))) void*)l, 16, 0, 0);
}

// ---------------- prep kernels ----------------

__global__ void mean_kernel(const float* __restrict__ enc, bf16* __restrict__ feat){
  int idx = blockIdx.x*256 + threadIdx.x;
  if (idx >= Bc*Fc) return;
  int b = idx >> 11, f = idx & (Fc-1);
  const float* p = enc + (size_t)b*Pc*Fc + f;
  float s = 0.f;
  for (int q = 0; q < Pc; ++q) s += p[(size_t)q*Fc];
  feat[idx] = (bf16)(s * (1.0f/(float)Pc));
}

__global__ void conv_kernel(const float* __restrict__ src, bf16* __restrict__ dst, int n){
  int i = blockIdx.x*256 + threadIdx.x;
  if (i < n) dst[i] = (bf16)src[i];
}

// W_ih (4096,512) -> permuted rows: row' = j*4+g  <-  row g*1024+j ; plain bf16
__global__ void permconv_ih(const float* __restrict__ W, bf16* __restrict__ Wp){
  int i = blockIdx.x*256 + threadIdx.x;
  if (i >= G4c*Ec) return;
  int rp = i >> 9, k = i & 511;
  int g = rp & 3, j = rp >> 2;
  Wp[i] = (bf16)W[(size_t)(g*Hc + j)*Ec + k];
}

// W_hh (4096,1024) -> permuted + split hi/lo
__global__ void permsplit_hh(const float* __restrict__ W, bf16* __restrict__ Whi, bf16* __restrict__ Wlo){
  int i = blockIdx.x*256 + threadIdx.x;
  if (i >= G4c*Hc) return;
  int rp = i >> 10, k = i & 1023;
  int g = rp & 3, j = rp >> 2;
  float v = W[(size_t)(g*Hc + j)*Hc + k];
  bf16 h = (bf16)v;
  Whi[i] = h; Wlo[i] = (bf16)(v - (float)h);
}

__global__ void split_kernel(const float* __restrict__ W, bf16* __restrict__ Whi, bf16* __restrict__ Wlo, int n){
  int i = blockIdx.x*256 + threadIdx.x;
  if (i >= n) return;
  float v = W[i]; bf16 h = (bf16)v;
  Whi[i] = h; Wlo[i] = (bf16)(v - (float)h);
}

__global__ void bcomb_kernel(const float* __restrict__ bih, const float* __restrict__ bhh, float* __restrict__ bc){
  int i = blockIdx.x*256 + threadIdx.x;
  if (i >= G4c) return;
  int g = i & 3, j = i >> 2;
  bc[i] = bih[g*Hc + j] + bhh[g*Hc + j];
}

// embedding gather into X_all rows 128..3967 (row = s*128+b holds x_s = emb_{s-1})
__global__ void gather_kernel(const float* __restrict__ emb, const int* __restrict__ gt, bf16* __restrict__ X){
  int idx = blockIdx.x*256 + threadIdx.x;
  if (idx >= MOUTc*(Ec/4)) return;
  int r = idx >> 7, ei = (idx & 127) * 4;
  int s = (r >> 7) + 1, b = r & 127;
  int tok = gt[b*(TMAXc+1) + (s-1)];
  const float* src = emb + (size_t)tok*Ec + ei;
  bf16* dst = X + (size_t)(s*Bc + b)*Ec + ei;
  dst[0]=(bf16)src[0]; dst[1]=(bf16)src[1]; dst[2]=(bf16)src[2]; dst[3]=(bf16)src[3];
}

// valid-row index build: meta[0]=R, meta[1+i]=row id (t*128+b), t-major, padded w/ 0
// lens sorted desc => valid set at step t is a prefix of b; pos = S(t)+b, S(t)=sum_b min(t,len[b]-1)
__global__ void build_ridx(const int* __restrict__ lens, int* __restrict__ meta){
  int i = blockIdx.x*256 + threadIdx.x;
  if (i >= MOUTc) return;
  int t = i >> 7, b = i & 127;
  int S = 0, R = 0;
  for (int bb = 0; bb < 128; ++bb) {
    int l = lens[bb] - 1;
    S += (t < l) ? t : l;
    R += l;
  }
  if (i == 0) meta[0] = R;
  if (i >= R) meta[1 + i] = 0;
  if (t < lens[b] - 1) meta[1 + S + b] = i;
}

// zero the masked output rows (valid rows are written by the FC GEMM)
__global__ void zerofill(const int* __restrict__ lens, float* __restrict__ out){
  int i = blockIdx.x*256 + threadIdx.x;
  if (i >= MOUTc*2500) return;
  int row = i / 2500, c4 = i - row*2500;
  int b = row / TMAXc, t = row - b*TMAXc;
  if (t >= lens[b] - 1) {
    float4 z = {0.f,0.f,0.f,0.f};
    *(float4*)(out + (size_t)row*Vc + c4*4) = z;
  }
}

// ---------------- generic MFMA GEMM (128x128 tile, BK=32, nt-major block order) ----------
// C[m,n] = sum_k A[m,k]*B[n,k]  (B is N x K row-major).
// EPI: 0 = x0 (sigmoid+BN), 1 = Xg (bias), 2 = FC (compacted rows via meta, bias, scatter)
template<int EPI, bool SPLIT>
__global__ __launch_bounds__(256, 2) void gemm_kernel(
  const bf16* __restrict__ Ahi, const bf16* __restrict__ Alo,
  const bf16* __restrict__ Bhi, const bf16* __restrict__ Blo,
  int M, int N, int K, int mtiles,
  const float* __restrict__ p0, const float* __restrict__ p1, const float* __restrict__ p2,
  bf16* __restrict__ outb, float* __restrict__ outf, const int* __restrict__ meta)
{
  constexpr int BK = 32;
  __shared__ alignas(16) bf16 sAh[128*BK], sBh[128*BK];
  __shared__ alignas(16) bf16 sAl[SPLIT ? 128*BK : 8], sBl[SPLIT ? 128*BK : 8];

  int tid = threadIdx.x;
  int lane = tid & 63, w = tid >> 6, wr = w >> 1, wc = w & 1;
  int bid = blockIdx.x;
  int nt = bid / mtiles, mt = bid - nt*mtiles;   // nt-major: B panel reused across consecutive blocks
  int m0 = mt*128, n0 = nt*128;

  int R = M;
  if constexpr (EPI == 2) {
    R = meta[0];
    if (m0 >= R) return;
  }

  // staging source rows (fixed per thread across the K loop)
  int sr = (tid*16) >> 6;            // 0..63
  int gr0, gr1;
  if constexpr (EPI == 2) { gr0 = meta[1 + m0 + sr]; gr1 = meta[1 + m0 + sr + 64]; }
  else                    { gr0 = m0 + sr;           gr1 = m0 + sr + 64; }

  f32x4 acc[4][4] = {};

  for (int kt = 0; kt < K; kt += BK) {
    #pragma unroll
    for (int is = 0; is < 2; ++is) {
      int p = tid*16 + is*4096;          // byte offset in 8KB tile
      int r = p >> 6, c = (p & 63) >> 1; // row, elem-col
      int ldsoff = w*512 + is*2048;      // elems (wave-uniform base)
      int ga = is ? gr1 : gr0;
      gll16(Ahi + (size_t)ga*K + kt + c, &sAh[ldsoff]);
      int rb = n0 + r; rb = rb < N ? rb : N - 1;
      gll16(Bhi + (size_t)rb*K + kt + c, &sBh[ldsoff]);
      if constexpr (SPLIT) {
        gll16(Alo + (size_t)ga*K + kt + c, &sAl[ldsoff]);
        gll16(Blo + (size_t)rb*K + kt + c, &sBl[ldsoff]);
      }
    }
    __syncthreads();

    int koff = (lane >> 4) * 8;
    bf16x8 ah[4], bh[4], al[SPLIT?4:1], bl[SPLIT?4:1];
    #pragma unroll
    for (int mi = 0; mi < 4; ++mi) {
      int rr = wr*64 + mi*16 + (lane & 15);
      ah[mi] = *(const bf16x8*)&sAh[rr*BK + koff];
      if constexpr (SPLIT) al[mi] = *(const bf16x8*)&sAl[rr*BK + koff];
    }
    #pragma unroll
    for (int ni = 0; ni < 4; ++ni) {
      int rr = wc*64 + ni*16 + (lane & 15);
      bh[ni] = *(const bf16x8*)&sBh[rr*BK + koff];
      if constexpr (SPLIT) bl[ni] = *(const bf16x8*)&sBl[rr*BK + koff];
    }
    #pragma unroll
    for (int mi = 0; mi < 4; ++mi)
      #pragma unroll
      for (int ni = 0; ni < 4; ++ni) {
        acc[mi][ni] = MFMA_B16(ah[mi], bh[ni], acc[mi][ni]);
        if constexpr (SPLIT) {
          acc[mi][ni] = MFMA_B16(ah[mi], bl[ni], acc[mi][ni]);
          acc[mi][ni] = MFMA_B16(al[mi], bh[ni], acc[mi][ni]);
        }
      }
    __syncthreads();
  }

  const float rbn = rsqrtf(1.0f + 1e-5f);
  #pragma unroll
  for (int mi = 0; mi < 4; ++mi) {
    #pragma unroll
    for (int ni = 0; ni < 4; ++ni) {
      int lrow = m0 + wr*64 + mi*16 + ((lane >> 4) << 2);
      int col = n0 + wc*64 + ni*16 + (lane & 15);
      #pragma unroll
      for (int j = 0; j < 4; ++j) {
        int rr = lrow + j;
        float v = acc[mi][ni][j];
        if constexpr (EPI == 0) {
          v = fsigm(v + p0[col]);
          v = p1[col]*(v*rbn) + p2[col];
          outb[(size_t)rr*Ec + col] = (bf16)v;
        } else if constexpr (EPI == 1) {
          outb[(size_t)rr*G4c + col] = (bf16)(v + p0[col]);
        } else {
          if (rr < R && col < N) {
            int val = meta[1 + rr];
            int t = val >> 7, b = val & 127;
            outf[(size_t)b*(TMAXc*Vc) + (size_t)t*Vc + col] = v + p0[col];
          }
        }
      }
    }
  }
}

// ---------------- persistent LSTM recurrence ----------------
// 256 blocks x 256 threads, 1 block/CU (128 KB LDS). Block (strip,rh):
// strip owns pcols [strip*32,+32), rh owns rows [rh*64,+64).
// Grid splits into TWO independent halves (rh=0/1) -> separate 128-block barriers.
// c-state lives in registers (lane-quad redundant). One spinner per block.

__device__ __forceinline__ void gridbar(int* cnt, int tgt){
  __syncthreads();                 // all block's h-stores issued
  if (threadIdx.x == 0) {
    __threadfence();               // release: flush this XCD's L2 to MALL
    __hip_atomic_fetch_add(cnt, 1, __ATOMIC_RELAXED, __HIP_MEMORY_SCOPE_AGENT);
    while (__hip_atomic_load(cnt, __ATOMIC_RELAXED, __HIP_MEMORY_SCOPE_AGENT) < tgt)
      __builtin_amdgcn_s_sleep(4);
    __threadfence();               // acquire: invalidate L1/L2 before reading fresh h
  }
  __syncthreads();
}

__global__ __launch_bounds__(256, 1) void lstm_persist(
  const bf16* __restrict__ Whi, const bf16* __restrict__ Wlo, // [4096][1024] permuted
  const bf16* __restrict__ Xg,                                 // [31*128][4096]
  bf16* hAh, bf16* hAl, bf16* hBh, bf16* hBl,                  // [128][1024] ping-pong
  bf16* __restrict__ Hh, bf16* __restrict__ Hl,                // [3840][1024]
  int* __restrict__ cnt)                                       // cnt[0]: rh0, cnt[64]: rh1
{
  extern __shared__ char sWc[];    // 128 KB: hi at 0, lo at +65536, swizzled
  int tid = threadIdx.x, lane = tid & 63, w = tid >> 6;
  int bid = blockIdx.x;
  int strip = bid >> 1, rh = bid & 1;
  int pc0 = strip * 32;
  int row0 = rh * 64 + w * 16;
  int* mycnt = cnt + rh * 64;

  // ---- fill W slice into LDS (one-time), swizzle byte ^= (p&7)<<4 ----
  for (int ch = tid; ch < 4096; ch += 256) {
    int p = ch >> 7;             // 0..31
    int k = (ch & 127) * 8;      // 0..1016
    bf16x8 vh = *(const bf16x8*)&Whi[(size_t)(pc0 + p)*Hc + k];
    bf16x8 vl = *(const bf16x8*)&Wlo[(size_t)(pc0 + p)*Hc + k];
    int be = (p*Hc + k)*2;
    int sw = (p & 7) << 4;
    *(bf16x8*)(sWc + (be ^ sw)) = vh;
    *(bf16x8*)(sWc + ((be + 65536) ^ sw)) = vl;
  }
  __syncthreads();

  int bp = lane & 15;            // frag row/col within 16
  int bk = (lane >> 4) << 3;     // frag k offset
  int bswz = (bp & 7) << 4;
  int rbase = row0 + ((lane >> 4) << 2);
  int e = lane & 3;

  const bf16 *hrh = hAh, *hrl = hAl;
  bf16 *hwh = hBh, *hwl = hBl;

  float creg[2][4] = {};
  float xgv[2][4];
  #pragma unroll
  for (int ni = 0; ni < 2; ++ni)
    #pragma unroll
    for (int j = 0; j < 4; ++j)
      xgv[ni][j] = (float)Xg[(size_t)(rbase + j)*G4c + pc0 + ni*16 + bp];

  #pragma unroll 1
  for (int s = 0; s < NSTEP; ++s) {
    f32x4 aHH[2], aHL[2], aLH[2];
    #pragma unroll
    for (int ni = 0; ni < 2; ++ni) {
      #pragma unroll
      for (int j = 0; j < 4; ++j) aHH[ni][j] = xgv[ni][j];
      aHL[ni] = (f32x4){0.f,0.f,0.f,0.f};
      aLH[ni] = (f32x4){0.f,0.f,0.f,0.f};
    }

    const bf16* pah = hrh + (size_t)(row0 + bp)*Hc + bk;
    const bf16* pal = hrl + (size_t)(row0 + bp)*Hc + bk;

    #pragma unroll
    for (int ks = 0; ks < 32; ++ks) {
      bf16x8 avh = *(const bf16x8*)(pah + ks*32);
      bf16x8 avl = *(const bf16x8*)(pal + ks*32);
      #pragma unroll
      for (int ni = 0; ni < 2; ++ni) {
        int be = ((ni*16 + bp)*Hc + ks*32 + bk)*2;
        bf16x8 bvh = *(const bf16x8*)(sWc + (be ^ bswz));
        bf16x8 bvl = *(const bf16x8*)(sWc + ((be + 65536) ^ bswz));
        aHH[ni] = MFMA_B16(avh, bvh, aHH[ni]);
        aHL[ni] = MFMA_B16(avh, bvl, aHL[ni]);
        aLH[ni] = MFMA_B16(avl, bvh, aLH[ni]);
      }
    }

    // ---- LSTM epilogue: combine 4 gates across lane-quads ----
    #pragma unroll
    for (int ni = 0; ni < 2; ++ni) {
      int pcol = pc0 + ni*16 + bp;
      int hcol = pcol >> 2;
      #pragma unroll
      for (int j = 0; j < 4; ++j) {
        int rr = rbase + j;
        float v = aHH[ni][j] + aHL[ni][j] + aLH[ni][j];
        float a  = v;
        float b1 = __shfl_xor(v, 1);
        float c2 = __shfl_xor(v, 2);
        float d3 = __shfl_xor(v, 3);
        int m;
        m = e;     float gI = (m==0)?a:(m==1)?b1:(m==2)?c2:d3;
        m = e ^ 1; float gF = (m==0)?a:(m==1)?b1:(m==2)?c2:d3;
        m = e ^ 2; float gG = (m==0)?a:(m==1)?b1:(m==2)?c2:d3;
        m = e ^ 3; float gO = (m==0)?a:(m==1)?b1:(m==2)?c2:d3;

        float co = creg[ni][j];
        float cn = fsigm(gF)*co + fsigm(gI)*ftanh(gG);
        float hn = fsigm(gO)*ftanh(cn);
        creg[ni][j] = cn;
        bf16 hhi = (bf16)hn;
        bf16 hlo = (bf16)(hn - (float)hhi);
        size_t oi = (size_t)rr*Hc + hcol;
        if (e == 1) hwh[oi] = hhi;
        else if (e == 2) hwl[oi] = hlo;
        if (s > 0) {
          size_t ho = (size_t)((s-1)*Bc + rr)*Hc + hcol;
          if (e == 0) Hh[ho] = hhi;
          else if (e == 3) Hl[ho] = hlo;
        }
      }
    }

    // prefetch next step's Xg before the barrier (independent of h)
    if (s + 1 < NSTEP) {
      #pragma unroll
      for (int ni = 0; ni < 2; ++ni)
        #pragma unroll
        for (int j = 0; j < 4; ++j)
          xgv[ni][j] = (float)Xg[(size_t)((s+1)*Bc + rbase + j)*G4c + pc0 + ni*16 + bp];
    }

    // swap ping-pong
    const bf16* t0 = hrh; hrh = hwh; hwh = (bf16*)t0;
    const bf16* t1 = hrl; hrl = hwl; hwl = (bf16*)t1;

    if (s < NSTEP - 1) gridbar(mycnt, (s + 1) * 128);
  }
}

// ---------------- launch ----------------

extern "C" void kernel_launch(void* const* d_in, const int* in_sizes, int n_in,
                              void* d_out, int out_size, void* d_ws, size_t ws_size,
                              hipStream_t stream)
{
  const float* enc   = (const float*)d_in[0];
  const int*   gt    = (const int*)  d_in[1];
  const int*   lens  = (const int*)  d_in[2];
  const float* emb   = (const float*)d_in[3];
  const float* Winit = (const float*)d_in[4];
  const float* binit = (const float*)d_in[5];
  const float* gam   = (const float*)d_in[6];
  const float* bet   = (const float*)d_in[7];
  const float* Wih   = (const float*)d_in[8];
  const float* bih   = (const float*)d_in[9];
  const float* Whh   = (const float*)d_in[10];
  const float* bhh   = (const float*)d_in[11];
  const float* Wfc   = (const float*)d_in[12];
  const float* bfc   = (const float*)d_in[13];
  float* out = (float*)d_out;

  char* ws = (char*)d_ws;
  size_t off = 0;
  auto alloc = [&](size_t bytes) -> char* {
    char* p = ws + off;
    off += (bytes + 255) & ~(size_t)255;
    return p;
  };

  bf16* featB  = (bf16*)alloc((size_t)Bc*Fc*2);
  bf16* WinitB = (bf16*)alloc((size_t)Ec*Fc*2);
  bf16* WihpB  = (bf16*)alloc((size_t)G4c*Ec*2);
  bf16* WhhHi  = (bf16*)alloc((size_t)G4c*Hc*2);
  bf16* WhhLo  = (bf16*)alloc((size_t)G4c*Hc*2);
  bf16* WfcHi  = (bf16*)alloc((size_t)Vc*Hc*2);
  bf16* WfcLo  = (bf16*)alloc((size_t)Vc*Hc*2);
  float* bcomb = (float*)alloc((size_t)G4c*4);
  bf16* Xall   = (bf16*)alloc((size_t)MALLc*Ec*2);
  bf16* Xg     = (bf16*)alloc((size_t)MALLc*G4c*2);
  bf16* h0h    = (bf16*)alloc((size_t)Bc*Hc*2);
  bf16* h0l    = (bf16*)alloc((size_t)Bc*Hc*2);
  bf16* h1h    = (bf16*)alloc((size_t)Bc*Hc*2);
  bf16* h1l    = (bf16*)alloc((size_t)Bc*Hc*2);
  bf16* HallH  = (bf16*)alloc((size_t)MOUTc*Hc*2);
  bf16* HallL  = (bf16*)alloc((size_t)MOUTc*Hc*2);
  int*  meta   = (int*) alloc((size_t)(1 + MOUTc)*4);
  int*  cnt    = (int*) alloc((size_t)128*4);

  if (off > ws_size) return;

  // zero initial state + barrier counters (captured in graph -> re-done every replay)
  hipMemsetAsync(h0h, 0, (size_t)Bc*Hc*2, stream);
  hipMemsetAsync(h0l, 0, (size_t)Bc*Hc*2, stream);
  hipMemsetAsync(cnt, 0, (size_t)128*4, stream);

  // prep
  mean_kernel<<<(Bc*Fc + 255)/256, 256, 0, stream>>>(enc, featB);
  conv_kernel<<<((Ec*Fc) + 255)/256, 256, 0, stream>>>(Winit, WinitB, Ec*Fc);
  permconv_ih<<<((G4c*Ec) + 255)/256, 256, 0, stream>>>(Wih, WihpB);
  permsplit_hh<<<((G4c*Hc) + 255)/256, 256, 0, stream>>>(Whh, WhhHi, WhhLo);
  split_kernel<<<((Vc*Hc) + 255)/256, 256, 0, stream>>>(Wfc, WfcHi, WfcLo, Vc*Hc);
  bcomb_kernel<<<(G4c + 255)/256, 256, 0, stream>>>(bih, bhh, bcomb);
  gather_kernel<<<((MOUTc*(Ec/4)) + 255)/256, 256, 0, stream>>>(emb, gt, Xall);
  build_ridx<<<(MOUTc + 255)/256, 256, 0, stream>>>(lens, meta);
  zerofill<<<(MOUTc*2500 + 255)/256, 256, 0, stream>>>(lens, out);

  // GEMM A: x0 = sigmoid(feat @ Winit^T + b) * BN -> X_all rows 0..127
  gemm_kernel<0,false><<<4, 256, 0, stream>>>(
      featB, nullptr, WinitB, nullptr, Bc, Ec, Fc, 1,
      binit, gam, bet, Xall, nullptr, nullptr);

  // GEMM C: Xg = X_all @ Wihp^T + bcomb   (3968 x 4096, K=512), nt-major
  gemm_kernel<1,false><<<31*32, 256, 0, stream>>>(
      Xall, nullptr, WihpB, nullptr, MALLc, G4c, Ec, 31,
      bcomb, nullptr, nullptr, Xg, nullptr, nullptr);

  // recurrence: one persistent kernel, 31 steps
  hipFuncSetAttribute(reinterpret_cast<const void*>(lstm_persist),
                      hipFuncAttributeMaxDynamicSharedMemorySize, 131072);
  lstm_persist<<<NBLK, 256, 131072, stream>>>(
      WhhHi, WhhLo, Xg, h0h, h0l, h1h, h1l, HallH, HallL, cnt);

  // GEMM E: preds = Hall[compacted] @ Wfc^T + b_fc -> scatter to out (split-3)
  gemm_kernel<2,true><<<79*30, 256, 0, stream>>>(
      HallH, HallL, WfcHi, WfcLo, MOUTc, Vc, Hc, 30,
      bfc, nullptr, nullptr, nullptr, out, meta);
}

// Round 4
// 958.112 us; speedup vs baseline: 2.8239x; 1.3560x over previous
//
#include <hip/hip_runtime.h>
#include <math.h>

typedef __bf16 bf16;
typedef __bf16 bf16x8 __attribute__((ext_vector_type(8)));
typedef __bf16 bf16x4 __attribute__((ext_vector_type(4)));
typedef float f32x4 __attribute__((ext_vector_type(4)));

#define MFMA_B16(a,b,c) __builtin_amdgcn_mfma_f32_16x16x32_bf16((a),(b),(c),0,0,0)

constexpr int TMAXc = 30;
constexpr int Bc = 128, Pc = 196, Fc = 2048, Ec = 512, Hc = 1024, Vc = 10000;
constexpr int G4c = 4 * Hc;          // 4096
constexpr int NSTEP = TMAXc + 1;     // 31
constexpr int MALLc = NSTEP * Bc;    // 3968
constexpr int MOUTc = TMAXc * Bc;    // 3840
constexpr int NBLK = 256;            // persistent kernel grid

__device__ __forceinline__ float fsigm(float x){
  return __fdividef(1.0f, 1.0f + __expf(-x));
}
__device__ __forceinline__ float ftanh(float x){
  return 1.0f - __fdividef(2.0f, __expf(2.0f*x) + 1.0f);
}

__device__ __forceinline__ void gll16(const void* g, void* l){
  __builtin_amdgcn_global_load_lds((const __attribute__((address_space(1))) void*)g,
                                   (__attribute__((address_space(3))) void*)l, 16, 0, 0);
}

// 16B load that bypasses L1/L2 (reads coherence point / MALL) via 2x u64 relaxed agent atomics
__device__ __forceinline__ bf16x8 ald16(const bf16* p){
  union { unsigned long long u[2]; bf16x8 v; } x;
  x.u[0] = __hip_atomic_load((const unsigned long long*)p,     __ATOMIC_RELAXED, __HIP_MEMORY_SCOPE_AGENT);
  x.u[1] = __hip_atomic_load((const unsigned long long*)p + 1, __ATOMIC_RELAXED, __HIP_MEMORY_SCOPE_AGENT);
  return x.v;
}
__device__ __forceinline__ void ast2(bf16* p, bf16 v){
  unsigned short b = __builtin_bit_cast(unsigned short, v);
  __hip_atomic_store((unsigned short*)p, b, __ATOMIC_RELAXED, __HIP_MEMORY_SCOPE_AGENT);
}

// ---------------- prep kernels ----------------

// 256 blocks: (b, half). Each thread: 4 cols, float4 loads over 196 rows.
__global__ void mean_kernel(const float* __restrict__ enc, bf16* __restrict__ feat){
  int blk = blockIdx.x, b = blk >> 1, half = blk & 1;
  int f0 = half*1024 + threadIdx.x*4;
  const float* p = enc + (size_t)b*Pc*Fc + f0;
  float4 s = {0.f,0.f,0.f,0.f};
  #pragma unroll 4
  for (int q = 0; q < Pc; ++q) {
    float4 v = *(const float4*)(p + (size_t)q*Fc);
    s.x += v.x; s.y += v.y; s.z += v.z; s.w += v.w;
  }
  const float r = 1.0f/(float)Pc;
  bf16x4 o = { (bf16)(s.x*r), (bf16)(s.y*r), (bf16)(s.z*r), (bf16)(s.w*r) };
  *(bf16x4*)&feat[b*Fc + f0] = o;
}

__global__ void conv_kernel(const float* __restrict__ src, bf16* __restrict__ dst, int n4){
  int i = blockIdx.x*256 + threadIdx.x;
  if (i >= n4) return;
  float4 v = ((const float4*)src)[i];
  bf16x4 o = { (bf16)v.x, (bf16)v.y, (bf16)v.z, (bf16)v.w };
  *(bf16x4*)&dst[i*4] = o;
}

// W_ih (4096,512) -> permuted rows: row' = j*4+g  <-  row g*1024+j ; plain bf16
__global__ void permconv_ih(const float* __restrict__ W, bf16* __restrict__ Wp){
  int i = blockIdx.x*256 + threadIdx.x;
  if (i >= G4c*Ec/4) return;
  int i4 = i*4;
  int rp = i4 >> 9, k = i4 & 511;
  int g = rp & 3, j = rp >> 2;
  float4 v = *(const float4*)&W[(size_t)(g*Hc + j)*Ec + k];
  bf16x4 o = { (bf16)v.x, (bf16)v.y, (bf16)v.z, (bf16)v.w };
  *(bf16x4*)&Wp[i4] = o;
}

// W_hh (4096,1024) -> permuted + split hi/lo
__global__ void permsplit_hh(const float* __restrict__ W, bf16* __restrict__ Whi, bf16* __restrict__ Wlo){
  int i = blockIdx.x*256 + threadIdx.x;
  if (i >= G4c*Hc/4) return;
  int i4 = i*4;
  int rp = i4 >> 10, k = i4 & 1023;
  int g = rp & 3, j = rp >> 2;
  float4 v = *(const float4*)&W[(size_t)(g*Hc + j)*Hc + k];
  bf16 h0=(bf16)v.x, h1=(bf16)v.y, h2=(bf16)v.z, h3=(bf16)v.w;
  bf16x4 hi = { h0, h1, h2, h3 };
  bf16x4 lo = { (bf16)(v.x-(float)h0), (bf16)(v.y-(float)h1), (bf16)(v.z-(float)h2), (bf16)(v.w-(float)h3) };
  *(bf16x4*)&Whi[i4] = hi;
  *(bf16x4*)&Wlo[i4] = lo;
}

__global__ void split_kernel(const float* __restrict__ W, bf16* __restrict__ Whi, bf16* __restrict__ Wlo, int n4){
  int i = blockIdx.x*256 + threadIdx.x;
  if (i >= n4) return;
  float4 v = ((const float4*)W)[i];
  bf16 h0=(bf16)v.x, h1=(bf16)v.y, h2=(bf16)v.z, h3=(bf16)v.w;
  bf16x4 hi = { h0, h1, h2, h3 };
  bf16x4 lo = { (bf16)(v.x-(float)h0), (bf16)(v.y-(float)h1), (bf16)(v.z-(float)h2), (bf16)(v.w-(float)h3) };
  *(bf16x4*)&Whi[i*4] = hi;
  *(bf16x4*)&Wlo[i*4] = lo;
}

__global__ void bcomb_kernel(const float* __restrict__ bih, const float* __restrict__ bhh, float* __restrict__ bc){
  int i = blockIdx.x*256 + threadIdx.x;
  if (i >= G4c) return;
  int g = i & 3, j = i >> 2;
  bc[i] = bih[g*Hc + j] + bhh[g*Hc + j];
}

// embedding gather into X_all rows 128..3967 (row = s*128+b holds x_s = emb_{s-1})
__global__ void gather_kernel(const float* __restrict__ emb, const int* __restrict__ gt, bf16* __restrict__ X){
  int idx = blockIdx.x*256 + threadIdx.x;
  if (idx >= MOUTc*(Ec/4)) return;
  int r = idx >> 7, ei = (idx & 127) * 4;
  int s = (r >> 7) + 1, b = r & 127;
  int tok = gt[b*(TMAXc+1) + (s-1)];
  float4 v = *(const float4*)(emb + (size_t)tok*Ec + ei);
  bf16x4 o = { (bf16)v.x, (bf16)v.y, (bf16)v.z, (bf16)v.w };
  *(bf16x4*)&X[(size_t)(s*Bc + b)*Ec + ei] = o;
}

// valid-row index build: meta[0]=R, meta[1+i]=row id (t*128+b), t-major, padded w/ 0
__global__ void build_ridx(const int* __restrict__ lens, int* __restrict__ meta){
  int i = blockIdx.x*256 + threadIdx.x;
  if (i >= MOUTc) return;
  int t = i >> 7, b = i & 127;
  int S = 0, R = 0;
  for (int bb = 0; bb < 128; ++bb) {
    int l = lens[bb] - 1;
    S += (t < l) ? t : l;
    R += l;
  }
  if (i == 0) meta[0] = R;
  if (i >= R) meta[1 + i] = 0;
  if (t < lens[b] - 1) meta[1 + S + b] = i;
}

// zero the masked output rows (valid rows are written by the FC GEMM)
__global__ void zerofill(const int* __restrict__ lens, float* __restrict__ out){
  int i = blockIdx.x*256 + threadIdx.x;
  if (i >= MOUTc*2500) return;
  int row = i / 2500, c4 = i - row*2500;
  int b = row / TMAXc, t = row - b*TMAXc;
  if (t >= lens[b] - 1) {
    float4 z = {0.f,0.f,0.f,0.f};
    *(float4*)(out + (size_t)row*Vc + c4*4) = z;
  }
}

// ---------------- generic MFMA GEMM (128x128 tile, BK=32, nt-major, XCD swizzle) --------
// C[m,n] = sum_k A[m,k]*B[n,k]  (B is N x K row-major).
// EPI: 0 = x0 (sigmoid+BN), 1 = Xg (bias), 2 = FC (compacted rows via meta, bias, scatter)
template<int EPI, bool SPLIT, bool XSWZ>
__global__ __launch_bounds__(256, 2) void gemm_kernel(
  const bf16* __restrict__ Ahi, const bf16* __restrict__ Alo,
  const bf16* __restrict__ Bhi, const bf16* __restrict__ Blo,
  int M, int N, int K, int mtiles,
  const float* __restrict__ p0, const float* __restrict__ p1, const float* __restrict__ p2,
  bf16* __restrict__ outb, float* __restrict__ outf, const int* __restrict__ meta)
{
  constexpr int BK = 32;
  __shared__ alignas(16) bf16 sAh[128*BK], sBh[128*BK];
  __shared__ alignas(16) bf16 sAl[SPLIT ? 128*BK : 8], sBl[SPLIT ? 128*BK : 8];

  int tid = threadIdx.x;
  int lane = tid & 63, w = tid >> 6, wr = w >> 1, wc = w & 1;
  int bid = blockIdx.x;
  if constexpr (XSWZ) {
    // bijective XCD swizzle (m204): same-nt blocks land on one XCD's L2
    int nwg = gridDim.x, q = nwg >> 3, r = nwg & 7;
    int x = bid & 7, o = bid >> 3;
    bid = (x < r ? x*(q+1) : r*(q+1) + (x-r)*q) + o;
  }
  int nt = bid / mtiles, mt = bid - nt*mtiles;   // nt-major: B panel reused across consecutive blocks
  int m0 = mt*128, n0 = nt*128;

  int R = M;
  if constexpr (EPI == 2) {
    R = meta[0];
    if (m0 >= R) return;
  }

  // staging source rows (fixed per thread across the K loop)
  int sr = (tid*16) >> 6;            // 0..63
  int gr0, gr1;
  if constexpr (EPI == 2) { gr0 = meta[1 + m0 + sr]; gr1 = meta[1 + m0 + sr + 64]; }
  else                    { gr0 = m0 + sr;           gr1 = m0 + sr + 64; }

  f32x4 acc[4][4] = {};

  for (int kt = 0; kt < K; kt += BK) {
    #pragma unroll
    for (int is = 0; is < 2; ++is) {
      int p = tid*16 + is*4096;          // byte offset in 8KB tile
      int r = p >> 6, c = (p & 63) >> 1; // row, elem-col
      int ldsoff = w*512 + is*2048;      // elems (wave-uniform base)
      int ga = is ? gr1 : gr0;
      gll16(Ahi + (size_t)ga*K + kt + c, &sAh[ldsoff]);
      int rb = n0 + r; rb = rb < N ? rb : N - 1;
      gll16(Bhi + (size_t)rb*K + kt + c, &sBh[ldsoff]);
      if constexpr (SPLIT) {
        gll16(Alo + (size_t)ga*K + kt + c, &sAl[ldsoff]);
        gll16(Blo + (size_t)rb*K + kt + c, &sBl[ldsoff]);
      }
    }
    __syncthreads();

    int koff = (lane >> 4) * 8;
    bf16x8 ah[4], bh[4], al[SPLIT?4:1], bl[SPLIT?4:1];
    #pragma unroll
    for (int mi = 0; mi < 4; ++mi) {
      int rr = wr*64 + mi*16 + (lane & 15);
      ah[mi] = *(const bf16x8*)&sAh[rr*BK + koff];
      if constexpr (SPLIT) al[mi] = *(const bf16x8*)&sAl[rr*BK + koff];
    }
    #pragma unroll
    for (int ni = 0; ni < 4; ++ni) {
      int rr = wc*64 + ni*16 + (lane & 15);
      bh[ni] = *(const bf16x8*)&sBh[rr*BK + koff];
      if constexpr (SPLIT) bl[ni] = *(const bf16x8*)&sBl[rr*BK + koff];
    }
    #pragma unroll
    for (int mi = 0; mi < 4; ++mi)
      #pragma unroll
      for (int ni = 0; ni < 4; ++ni) {
        acc[mi][ni] = MFMA_B16(ah[mi], bh[ni], acc[mi][ni]);
        if constexpr (SPLIT) {
          acc[mi][ni] = MFMA_B16(ah[mi], bl[ni], acc[mi][ni]);
          acc[mi][ni] = MFMA_B16(al[mi], bh[ni], acc[mi][ni]);
        }
      }
    __syncthreads();
  }

  const float rbn = rsqrtf(1.0f + 1e-5f);
  #pragma unroll
  for (int mi = 0; mi < 4; ++mi) {
    #pragma unroll
    for (int ni = 0; ni < 4; ++ni) {
      int lrow = m0 + wr*64 + mi*16 + ((lane >> 4) << 2);
      int col = n0 + wc*64 + ni*16 + (lane & 15);
      #pragma unroll
      for (int j = 0; j < 4; ++j) {
        int rr = lrow + j;
        float v = acc[mi][ni][j];
        if constexpr (EPI == 0) {
          v = fsigm(v + p0[col]);
          v = p1[col]*(v*rbn) + p2[col];
          outb[(size_t)rr*Ec + col] = (bf16)v;
        } else if constexpr (EPI == 1) {
          outb[(size_t)rr*G4c + col] = (bf16)(v + p0[col]);
        } else {
          if (rr < R && col < N) {
            int val = meta[1 + rr];
            int t = val >> 7, b = val & 127;
            outf[(size_t)b*(TMAXc*Vc) + (size_t)t*Vc + col] = v + p0[col];
          }
        }
      }
    }
  }
}

// ---------------- persistent LSTM recurrence ----------------
// 256 blocks x 256 threads, 1 block/CU (128 KB LDS). Block (strip,rh):
// strip owns pcols [strip*32,+32), rh owns rows [rh*64,+64).
// h is exchanged through the MALL with agent-scope RELAXED atomics (L1/L2 bypass):
// no fences, no cache invalidates -> L2 stays warm for Xg. One spinner per block.

__device__ __forceinline__ void gridbar(int* cnt, int tgt){
  __syncthreads();                 // drains vmcnt(0): all h atomic-stores are at MALL
  if (threadIdx.x == 0) {
    __hip_atomic_fetch_add(cnt, 1, __ATOMIC_RELAXED, __HIP_MEMORY_SCOPE_AGENT);
    while (__hip_atomic_load(cnt, __ATOMIC_RELAXED, __HIP_MEMORY_SCOPE_AGENT) < tgt)
      __builtin_amdgcn_s_sleep(1);
  }
  __syncthreads();
}

__global__ __launch_bounds__(256, 1) void lstm_persist(
  const bf16* __restrict__ Whi, const bf16* __restrict__ Wlo, // [4096][1024] permuted
  const bf16* __restrict__ Xg,                                 // [31*128][4096]
  bf16* hAh, bf16* hAl, bf16* hBh, bf16* hBl,                  // [128][1024] ping-pong
  bf16* __restrict__ Hh, bf16* __restrict__ Hl,                // [3840][1024]
  int* __restrict__ cnt)                                       // cnt[0]: rh0, cnt[64]: rh1
{
  extern __shared__ char sWc[];    // 128 KB: hi at 0, lo at +65536, swizzled
  int tid = threadIdx.x, lane = tid & 63, w = tid >> 6;
  int bid = blockIdx.x;
  int strip = bid >> 1, rh = bid & 1;
  int pc0 = strip * 32;
  int row0 = rh * 64 + w * 16;
  int* mycnt = cnt + rh * 64;

  // ---- fill W slice into LDS (one-time), swizzle byte ^= (p&7)<<4 ----
  for (int ch = tid; ch < 4096; ch += 256) {
    int p = ch >> 7;             // 0..31
    int k = (ch & 127) * 8;      // 0..1016
    bf16x8 vh = *(const bf16x8*)&Whi[(size_t)(pc0 + p)*Hc + k];
    bf16x8 vl = *(const bf16x8*)&Wlo[(size_t)(pc0 + p)*Hc + k];
    int be = (p*Hc + k)*2;
    int sw = (p & 7) << 4;
    *(bf16x8*)(sWc + (be ^ sw)) = vh;
    *(bf16x8*)(sWc + ((be + 65536) ^ sw)) = vl;
  }
  __syncthreads();

  int bp = lane & 15;            // frag row/col within 16
  int bk = (lane >> 4) << 3;     // frag k offset
  int bswz = (bp & 7) << 4;
  int rbase = row0 + ((lane >> 4) << 2);
  int e = lane & 3;

  const bf16 *hrh = hAh, *hrl = hAl;
  bf16 *hwh = hBh, *hwl = hBl;

  float creg[2][4] = {};
  float xgv[2][4];
  #pragma unroll
  for (int ni = 0; ni < 2; ++ni)
    #pragma unroll
    for (int j = 0; j < 4; ++j)
      xgv[ni][j] = (float)Xg[(size_t)(rbase + j)*G4c + pc0 + ni*16 + bp];

  #pragma unroll 1
  for (int s = 0; s < NSTEP; ++s) {
    f32x4 aHH[2], aHL[2], aLH[2];
    #pragma unroll
    for (int ni = 0; ni < 2; ++ni) {
      #pragma unroll
      for (int j = 0; j < 4; ++j) aHH[ni][j] = xgv[ni][j];
      aHL[ni] = (f32x4){0.f,0.f,0.f,0.f};
      aLH[ni] = (f32x4){0.f,0.f,0.f,0.f};
    }

    const bf16* pah = hrh + (size_t)(row0 + bp)*Hc + bk;
    const bf16* pal = hrl + (size_t)(row0 + bp)*Hc + bk;

    #pragma unroll
    for (int ks = 0; ks < 32; ++ks) {
      bf16x8 avh = ald16(pah + ks*32);
      bf16x8 avl = ald16(pal + ks*32);
      #pragma unroll
      for (int ni = 0; ni < 2; ++ni) {
        int be = ((ni*16 + bp)*Hc + ks*32 + bk)*2;
        bf16x8 bvh = *(const bf16x8*)(sWc + (be ^ bswz));
        bf16x8 bvl = *(const bf16x8*)(sWc + ((be + 65536) ^ bswz));
        aHH[ni] = MFMA_B16(avh, bvh, aHH[ni]);
        aHL[ni] = MFMA_B16(avh, bvl, aHL[ni]);
        aLH[ni] = MFMA_B16(avl, bvh, aLH[ni]);
      }
    }

    // ---- LSTM epilogue: combine 4 gates across lane-quads ----
    #pragma unroll
    for (int ni = 0; ni < 2; ++ni) {
      int pcol = pc0 + ni*16 + bp;
      int hcol = pcol >> 2;
      #pragma unroll
      for (int j = 0; j < 4; ++j) {
        int rr = rbase + j;
        float v = aHH[ni][j] + aHL[ni][j] + aLH[ni][j];
        float a  = v;
        float b1 = __shfl_xor(v, 1);
        float c2 = __shfl_xor(v, 2);
        float d3 = __shfl_xor(v, 3);
        int m;
        m = e;     float gI = (m==0)?a:(m==1)?b1:(m==2)?c2:d3;
        m = e ^ 1; float gF = (m==0)?a:(m==1)?b1:(m==2)?c2:d3;
        m = e ^ 2; float gG = (m==0)?a:(m==1)?b1:(m==2)?c2:d3;
        m = e ^ 3; float gO = (m==0)?a:(m==1)?b1:(m==2)?c2:d3;

        float co = creg[ni][j];
        float cn = fsigm(gF)*co + fsigm(gI)*ftanh(gG);
        float hn = fsigm(gO)*ftanh(cn);
        creg[ni][j] = cn;
        bf16 hhi = (bf16)hn;
        bf16 hlo = (bf16)(hn - (float)hhi);
        size_t oi = (size_t)rr*Hc + hcol;
        if (e == 1) ast2(&hwh[oi], hhi);
        else if (e == 2) ast2(&hwl[oi], hlo);
        if (s > 0) {
          size_t ho = (size_t)((s-1)*Bc + rr)*Hc + hcol;
          if (e == 0) Hh[ho] = hhi;
          else if (e == 3) Hl[ho] = hlo;
        }
      }
    }

    // prefetch next step's Xg before the barrier (independent of h; L2 stays warm now)
    if (s + 1 < NSTEP) {
      #pragma unroll
      for (int ni = 0; ni < 2; ++ni)
        #pragma unroll
        for (int j = 0; j < 4; ++j)
          xgv[ni][j] = (float)Xg[(size_t)((s+1)*Bc + rbase + j)*G4c + pc0 + ni*16 + bp];
    }

    // swap ping-pong
    const bf16* t0 = hrh; hrh = hwh; hwh = (bf16*)t0;
    const bf16* t1 = hrl; hrl = hwl; hwl = (bf16*)t1;

    if (s < NSTEP - 1) gridbar(mycnt, (s + 1) * 128);
  }
}

// ---------------- launch ----------------

extern "C" void kernel_launch(void* const* d_in, const int* in_sizes, int n_in,
                              void* d_out, int out_size, void* d_ws, size_t ws_size,
                              hipStream_t stream)
{
  const float* enc   = (const float*)d_in[0];
  const int*   gt    = (const int*)  d_in[1];
  const int*   lens  = (const int*)  d_in[2];
  const float* emb   = (const float*)d_in[3];
  const float* Winit = (const float*)d_in[4];
  const float* binit = (const float*)d_in[5];
  const float* gam   = (const float*)d_in[6];
  const float* bet   = (const float*)d_in[7];
  const float* Wih   = (const float*)d_in[8];
  const float* bih   = (const float*)d_in[9];
  const float* Whh   = (const float*)d_in[10];
  const float* bhh   = (const float*)d_in[11];
  const float* Wfc   = (const float*)d_in[12];
  const float* bfc   = (const float*)d_in[13];
  float* out = (float*)d_out;

  char* ws = (char*)d_ws;
  size_t off = 0;
  auto alloc = [&](size_t bytes) -> char* {
    char* p = ws + off;
    off += (bytes + 255) & ~(size_t)255;
    return p;
  };

  bf16* featB  = (bf16*)alloc((size_t)Bc*Fc*2);
  bf16* WinitB = (bf16*)alloc((size_t)Ec*Fc*2);
  bf16* WihpB  = (bf16*)alloc((size_t)G4c*Ec*2);
  bf16* WhhHi  = (bf16*)alloc((size_t)G4c*Hc*2);
  bf16* WhhLo  = (bf16*)alloc((size_t)G4c*Hc*2);
  bf16* WfcHi  = (bf16*)alloc((size_t)Vc*Hc*2);
  bf16* WfcLo  = (bf16*)alloc((size_t)Vc*Hc*2);
  float* bcomb = (float*)alloc((size_t)G4c*4);
  bf16* Xall   = (bf16*)alloc((size_t)MALLc*Ec*2);
  bf16* Xg     = (bf16*)alloc((size_t)MALLc*G4c*2);
  bf16* h0h    = (bf16*)alloc((size_t)Bc*Hc*2);
  bf16* h0l    = (bf16*)alloc((size_t)Bc*Hc*2);
  bf16* h1h    = (bf16*)alloc((size_t)Bc*Hc*2);
  bf16* h1l    = (bf16*)alloc((size_t)Bc*Hc*2);
  bf16* HallH  = (bf16*)alloc((size_t)MOUTc*Hc*2);
  bf16* HallL  = (bf16*)alloc((size_t)MOUTc*Hc*2);
  int*  meta   = (int*) alloc((size_t)(1 + MOUTc)*4);
  int*  cnt    = (int*) alloc((size_t)128*4);

  if (off > ws_size) return;

  // zero initial state + barrier counters (captured in graph -> re-done every replay)
  hipMemsetAsync(h0h, 0, (size_t)Bc*Hc*2, stream);
  hipMemsetAsync(h0l, 0, (size_t)Bc*Hc*2, stream);
  hipMemsetAsync(cnt, 0, (size_t)128*4, stream);

  // prep
  mean_kernel<<<256, 256, 0, stream>>>(enc, featB);
  conv_kernel<<<(Ec*Fc/4 + 255)/256, 256, 0, stream>>>(Winit, WinitB, Ec*Fc/4);
  permconv_ih<<<(G4c*Ec/4 + 255)/256, 256, 0, stream>>>(Wih, WihpB);
  permsplit_hh<<<(G4c*Hc/4 + 255)/256, 256, 0, stream>>>(Whh, WhhHi, WhhLo);
  split_kernel<<<(Vc*Hc/4 + 255)/256, 256, 0, stream>>>(Wfc, WfcHi, WfcLo, Vc*Hc/4);
  bcomb_kernel<<<(G4c + 255)/256, 256, 0, stream>>>(bih, bhh, bcomb);
  gather_kernel<<<(MOUTc*(Ec/4) + 255)/256, 256, 0, stream>>>(emb, gt, Xall);
  build_ridx<<<(MOUTc + 255)/256, 256, 0, stream>>>(lens, meta);
  zerofill<<<(MOUTc*2500 + 255)/256, 256, 0, stream>>>(lens, out);

  // GEMM A: x0 = sigmoid(feat @ Winit^T + b) * BN -> X_all rows 0..127
  gemm_kernel<0,false,false><<<4, 256, 0, stream>>>(
      featB, nullptr, WinitB, nullptr, Bc, Ec, Fc, 1,
      binit, gam, bet, Xall, nullptr, nullptr);

  // GEMM C: Xg = X_all @ Wihp^T + bcomb   (3968 x 4096, K=512), nt-major + XCD swizzle
  gemm_kernel<1,false,true><<<31*32, 256, 0, stream>>>(
      Xall, nullptr, WihpB, nullptr, MALLc, G4c, Ec, 31,
      bcomb, nullptr, nullptr, Xg, nullptr, nullptr);

  // recurrence: one persistent kernel, 31 steps
  hipFuncSetAttribute(reinterpret_cast<const void*>(lstm_persist),
                      hipFuncAttributeMaxDynamicSharedMemorySize, 131072);
  lstm_persist<<<NBLK, 256, 131072, stream>>>(
      WhhHi, WhhLo, Xg, h0h, h0l, h1h, h1l, HallH, HallL, cnt);

  // GEMM E: preds = Hall[compacted] @ Wfc^T + b_fc -> scatter to out (split-3 + XCD swizzle)
  gemm_kernel<2,true,true><<<79*30, 256, 0, stream>>>(
      HallH, HallL, WfcHi, WfcLo, MOUTc, Vc, Hc, 30,
      bfc, nullptr, nullptr, nullptr, out, meta);
}

// Round 5
// 851.263 us; speedup vs baseline: 3.1784x; 1.1255x over previous
//
#include <hip/hip_runtime.h>
#include <math.h>

typedef __bf16 bf16;
typedef __bf16 bf16x8 __attribute__((ext_vector_type(8)));
typedef __bf16 bf16x4 __attribute__((ext_vector_type(4)));
typedef float f32x4 __attribute__((ext_vector_type(4)));

#define MFMA_B16(a,b,c) __builtin_amdgcn_mfma_f32_16x16x32_bf16((a),(b),(c),0,0,0)

constexpr int TMAXc = 30;
constexpr int Bc = 128, Pc = 196, Fc = 2048, Ec = 512, Hc = 1024, Vc = 10000;
constexpr int G4c = 4 * Hc;          // 4096
constexpr int NSTEP = TMAXc + 1;     // 31
constexpr int MALLc = NSTEP * Bc;    // 3968
constexpr int MOUTc = TMAXc * Bc;    // 3840
constexpr int NBLK = 256;            // persistent kernel grid

__device__ __forceinline__ float fsigm(float x){
  return __fdividef(1.0f, 1.0f + __expf(-x));
}
__device__ __forceinline__ float ftanh(float x){
  return 1.0f - __fdividef(2.0f, __expf(2.0f*x) + 1.0f);
}

__device__ __forceinline__ void gll16(const void* g, void* l){
  __builtin_amdgcn_global_load_lds((const __attribute__((address_space(1))) void*)g,
                                   (__attribute__((address_space(3))) void*)l, 16, 0, 0);
}

// 2B agent-scope write-through store (h goes to MALL; no fence/invalidate needed)
__device__ __forceinline__ void ast2(bf16* p, bf16 v){
  unsigned short b = __builtin_bit_cast(unsigned short, v);
  __hip_atomic_store((unsigned short*)p, b, __ATOMIC_RELAXED, __HIP_MEMORY_SCOPE_AGENT);
}

// ---------------- prep kernels ----------------

// 256 blocks: (b, half). Each thread: 4 cols, float4 loads over 196 rows.
__global__ void mean_kernel(const float* __restrict__ enc, bf16* __restrict__ feat){
  int blk = blockIdx.x, b = blk >> 1, half = blk & 1;
  int f0 = half*1024 + threadIdx.x*4;
  const float* p = enc + (size_t)b*Pc*Fc + f0;
  float4 s = {0.f,0.f,0.f,0.f};
  #pragma unroll 4
  for (int q = 0; q < Pc; ++q) {
    float4 v = *(const float4*)(p + (size_t)q*Fc);
    s.x += v.x; s.y += v.y; s.z += v.z; s.w += v.w;
  }
  const float r = 1.0f/(float)Pc;
  bf16x4 o = { (bf16)(s.x*r), (bf16)(s.y*r), (bf16)(s.z*r), (bf16)(s.w*r) };
  *(bf16x4*)&feat[b*Fc + f0] = o;
}

__global__ void conv_kernel(const float* __restrict__ src, bf16* __restrict__ dst, int n4){
  int i = blockIdx.x*256 + threadIdx.x;
  if (i >= n4) return;
  float4 v = ((const float4*)src)[i];
  bf16x4 o = { (bf16)v.x, (bf16)v.y, (bf16)v.z, (bf16)v.w };
  *(bf16x4*)&dst[i*4] = o;
}

// W_ih (4096,512) -> permuted rows: row' = j*4+g  <-  row g*1024+j ; plain bf16
__global__ void permconv_ih(const float* __restrict__ W, bf16* __restrict__ Wp){
  int i = blockIdx.x*256 + threadIdx.x;
  if (i >= G4c*Ec/4) return;
  int i4 = i*4;
  int rp = i4 >> 9, k = i4 & 511;
  int g = rp & 3, j = rp >> 2;
  float4 v = *(const float4*)&W[(size_t)(g*Hc + j)*Ec + k];
  bf16x4 o = { (bf16)v.x, (bf16)v.y, (bf16)v.z, (bf16)v.w };
  *(bf16x4*)&Wp[i4] = o;
}

// W_hh (4096,1024) -> permuted + split hi/lo
__global__ void permsplit_hh(const float* __restrict__ W, bf16* __restrict__ Whi, bf16* __restrict__ Wlo){
  int i = blockIdx.x*256 + threadIdx.x;
  if (i >= G4c*Hc/4) return;
  int i4 = i*4;
  int rp = i4 >> 10, k = i4 & 1023;
  int g = rp & 3, j = rp >> 2;
  float4 v = *(const float4*)&W[(size_t)(g*Hc + j)*Hc + k];
  bf16 h0=(bf16)v.x, h1=(bf16)v.y, h2=(bf16)v.z, h3=(bf16)v.w;
  bf16x4 hi = { h0, h1, h2, h3 };
  bf16x4 lo = { (bf16)(v.x-(float)h0), (bf16)(v.y-(float)h1), (bf16)(v.z-(float)h2), (bf16)(v.w-(float)h3) };
  *(bf16x4*)&Whi[i4] = hi;
  *(bf16x4*)&Wlo[i4] = lo;
}

__global__ void split_kernel(const float* __restrict__ W, bf16* __restrict__ Whi, bf16* __restrict__ Wlo, int n4){
  int i = blockIdx.x*256 + threadIdx.x;
  if (i >= n4) return;
  float4 v = ((const float4*)W)[i];
  bf16 h0=(bf16)v.x, h1=(bf16)v.y, h2=(bf16)v.z, h3=(bf16)v.w;
  bf16x4 hi = { h0, h1, h2, h3 };
  bf16x4 lo = { (bf16)(v.x-(float)h0), (bf16)(v.y-(float)h1), (bf16)(v.z-(float)h2), (bf16)(v.w-(float)h3) };
  *(bf16x4*)&Whi[i*4] = hi;
  *(bf16x4*)&Wlo[i*4] = lo;
}

__global__ void bcomb_kernel(const float* __restrict__ bih, const float* __restrict__ bhh, float* __restrict__ bc){
  int i = blockIdx.x*256 + threadIdx.x;
  if (i >= G4c) return;
  int g = i & 3, j = i >> 2;
  bc[i] = bih[g*Hc + j] + bhh[g*Hc + j];
}

// embedding gather into X_all rows 128..3967 (row = s*128+b holds x_s = emb_{s-1})
__global__ void gather_kernel(const float* __restrict__ emb, const int* __restrict__ gt, bf16* __restrict__ X){
  int idx = blockIdx.x*256 + threadIdx.x;
  if (idx >= MOUTc*(Ec/4)) return;
  int r = idx >> 7, ei = (idx & 127) * 4;
  int s = (r >> 7) + 1, b = r & 127;
  int tok = gt[b*(TMAXc+1) + (s-1)];
  float4 v = *(const float4*)(emb + (size_t)tok*Ec + ei);
  bf16x4 o = { (bf16)v.x, (bf16)v.y, (bf16)v.z, (bf16)v.w };
  *(bf16x4*)&X[(size_t)(s*Bc + b)*Ec + ei] = o;
}

// valid-row index build: meta[0]=R, meta[1+i]=row id (t*128+b), t-major, padded w/ 0
__global__ void build_ridx(const int* __restrict__ lens, int* __restrict__ meta){
  int i = blockIdx.x*256 + threadIdx.x;
  if (i >= MOUTc) return;
  int t = i >> 7, b = i & 127;
  int S = 0, R = 0;
  for (int bb = 0; bb < 128; ++bb) {
    int l = lens[bb] - 1;
    S += (t < l) ? t : l;
    R += l;
  }
  if (i == 0) meta[0] = R;
  if (i >= R) meta[1 + i] = 0;
  if (t < lens[b] - 1) meta[1 + S + b] = i;
}

// zero the masked output rows (valid rows are written by the FC GEMM)
__global__ void zerofill(const int* __restrict__ lens, float* __restrict__ out){
  int i = blockIdx.x*256 + threadIdx.x;
  if (i >= MOUTc*2500) return;
  int row = i / 2500, c4 = i - row*2500;
  int b = row / TMAXc, t = row - b*TMAXc;
  if (t >= lens[b] - 1) {
    float4 z = {0.f,0.f,0.f,0.f};
    *(float4*)(out + (size_t)row*Vc + c4*4) = z;
  }
}

// ---------------- generic MFMA GEMM (128x128 tile, BK=32, nt-major, XCD swizzle) --------
// C[m,n] = sum_k A[m,k]*B[n,k]  (B is N x K row-major).
// EPI: 0 = x0 (sigmoid+BN), 1 = Xg (bias), 2 = FC (compacted rows via meta, bias, scatter)
template<int EPI, bool SPLIT, bool XSWZ>
__global__ __launch_bounds__(256, 2) void gemm_kernel(
  const bf16* __restrict__ Ahi, const bf16* __restrict__ Alo,
  const bf16* __restrict__ Bhi, const bf16* __restrict__ Blo,
  int M, int N, int K, int mtiles,
  const float* __restrict__ p0, const float* __restrict__ p1, const float* __restrict__ p2,
  bf16* __restrict__ outb, float* __restrict__ outf, const int* __restrict__ meta)
{
  constexpr int BK = 32;
  __shared__ alignas(16) bf16 sAh[128*BK], sBh[128*BK];
  __shared__ alignas(16) bf16 sAl[SPLIT ? 128*BK : 8], sBl[SPLIT ? 128*BK : 8];

  int tid = threadIdx.x;
  int lane = tid & 63, w = tid >> 6, wr = w >> 1, wc = w & 1;
  int bid = blockIdx.x;
  if constexpr (XSWZ) {
    // bijective XCD swizzle (m204): same-nt blocks land on one XCD's L2
    int nwg = gridDim.x, q = nwg >> 3, r = nwg & 7;
    int x = bid & 7, o = bid >> 3;
    bid = (x < r ? x*(q+1) : r*(q+1) + (x-r)*q) + o;
  }
  int nt = bid / mtiles, mt = bid - nt*mtiles;   // nt-major: B panel reused across consecutive blocks
  int m0 = mt*128, n0 = nt*128;

  int R = M;
  if constexpr (EPI == 2) {
    R = meta[0];
    if (m0 >= R) return;
  }

  // staging source rows (fixed per thread across the K loop)
  int sr = (tid*16) >> 6;            // 0..63
  int gr0, gr1;
  if constexpr (EPI == 2) { gr0 = meta[1 + m0 + sr]; gr1 = meta[1 + m0 + sr + 64]; }
  else                    { gr0 = m0 + sr;           gr1 = m0 + sr + 64; }

  f32x4 acc[4][4] = {};

  for (int kt = 0; kt < K; kt += BK) {
    #pragma unroll
    for (int is = 0; is < 2; ++is) {
      int p = tid*16 + is*4096;          // byte offset in 8KB tile
      int r = p >> 6, c = (p & 63) >> 1; // row, elem-col
      int ldsoff = w*512 + is*2048;      // elems (wave-uniform base)
      int ga = is ? gr1 : gr0;
      gll16(Ahi + (size_t)ga*K + kt + c, &sAh[ldsoff]);
      int rb = n0 + r; rb = rb < N ? rb : N - 1;
      gll16(Bhi + (size_t)rb*K + kt + c, &sBh[ldsoff]);
      if constexpr (SPLIT) {
        gll16(Alo + (size_t)ga*K + kt + c, &sAl[ldsoff]);
        gll16(Blo + (size_t)rb*K + kt + c, &sBl[ldsoff]);
      }
    }
    __syncthreads();

    int koff = (lane >> 4) * 8;
    bf16x8 ah[4], bh[4], al[SPLIT?4:1], bl[SPLIT?4:1];
    #pragma unroll
    for (int mi = 0; mi < 4; ++mi) {
      int rr = wr*64 + mi*16 + (lane & 15);
      ah[mi] = *(const bf16x8*)&sAh[rr*BK + koff];
      if constexpr (SPLIT) al[mi] = *(const bf16x8*)&sAl[rr*BK + koff];
    }
    #pragma unroll
    for (int ni = 0; ni < 4; ++ni) {
      int rr = wc*64 + ni*16 + (lane & 15);
      bh[ni] = *(const bf16x8*)&sBh[rr*BK + koff];
      if constexpr (SPLIT) bl[ni] = *(const bf16x8*)&sBl[rr*BK + koff];
    }
    #pragma unroll
    for (int mi = 0; mi < 4; ++mi)
      #pragma unroll
      for (int ni = 0; ni < 4; ++ni) {
        acc[mi][ni] = MFMA_B16(ah[mi], bh[ni], acc[mi][ni]);
        if constexpr (SPLIT) {
          acc[mi][ni] = MFMA_B16(ah[mi], bl[ni], acc[mi][ni]);
          acc[mi][ni] = MFMA_B16(al[mi], bh[ni], acc[mi][ni]);
        }
      }
    __syncthreads();
  }

  const float rbn = rsqrtf(1.0f + 1e-5f);
  #pragma unroll
  for (int mi = 0; mi < 4; ++mi) {
    #pragma unroll
    for (int ni = 0; ni < 4; ++ni) {
      int lrow = m0 + wr*64 + mi*16 + ((lane >> 4) << 2);
      int col = n0 + wc*64 + ni*16 + (lane & 15);
      #pragma unroll
      for (int j = 0; j < 4; ++j) {
        int rr = lrow + j;
        float v = acc[mi][ni][j];
        if constexpr (EPI == 0) {
          v = fsigm(v + p0[col]);
          v = p1[col]*(v*rbn) + p2[col];
          outb[(size_t)rr*Ec + col] = (bf16)v;
        } else if constexpr (EPI == 1) {
          outb[(size_t)rr*G4c + col] = (bf16)(v + p0[col]);
        } else {
          if (rr < R && col < N) {
            int val = meta[1 + rr];
            int t = val >> 7, b = val & 127;
            outf[(size_t)b*(TMAXc*Vc) + (size_t)t*Vc + col] = v + p0[col];
          }
        }
      }
    }
  }
}

// ---------------- persistent LSTM recurrence ----------------
// 256 blocks x 256 threads, 1 block/CU (128 KB LDS). Block (strip,rh):
// strip owns pcols [strip*32,+32), rh owns rows [rh*64,+64).
// h_s lives in a FRESH 32-slot chain: producer agent-store (write-through to MALL),
// consumer NORMAL cached loads (no stale copy can exist: addresses never read
// before their write in this dispatch; L1/L2 invalidated at dispatch start).
// Per XCD the h slice is fetched from MALL once, then L2-served.

__device__ __forceinline__ void gridbar(int* cnt, int tgt){
  __syncthreads();                 // drains vmcnt(0): all h agent-stores are at MALL
  if (threadIdx.x == 0) {
    __hip_atomic_fetch_add(cnt, 1, __ATOMIC_RELAXED, __HIP_MEMORY_SCOPE_AGENT);
    while (__hip_atomic_load(cnt, __ATOMIC_RELAXED, __HIP_MEMORY_SCOPE_AGENT) < tgt)
      __builtin_amdgcn_s_sleep(1);
  }
  __syncthreads();
}

__global__ __launch_bounds__(256, 1) void lstm_persist(
  const bf16* __restrict__ Whi, const bf16* __restrict__ Wlo, // [4096][1024] permuted
  const bf16* __restrict__ Xg,                                 // [31*128][4096]
  bf16* __restrict__ hCh, bf16* __restrict__ hCl,              // [32][128][1024] chains, slot0 zeroed
  bf16* __restrict__ Hh, bf16* __restrict__ Hl,                // [3840][1024]
  int* __restrict__ cnt)                                       // cnt[0]: rh0, cnt[64]: rh1
{
  extern __shared__ char sWc[];    // 128 KB: hi at 0, lo at +65536, swizzled
  int tid = threadIdx.x, lane = tid & 63, w = tid >> 6;
  int bid = blockIdx.x;
  int strip = bid >> 1, rh = bid & 1;
  int pc0 = strip * 32;
  int row0 = rh * 64 + w * 16;
  int* mycnt = cnt + rh * 64;

  // ---- fill W slice into LDS (one-time), swizzle byte ^= (p&7)<<4 ----
  for (int ch = tid; ch < 4096; ch += 256) {
    int p = ch >> 7;             // 0..31
    int k = (ch & 127) * 8;      // 0..1016
    bf16x8 vh = *(const bf16x8*)&Whi[(size_t)(pc0 + p)*Hc + k];
    bf16x8 vl = *(const bf16x8*)&Wlo[(size_t)(pc0 + p)*Hc + k];
    int be = (p*Hc + k)*2;
    int sw = (p & 7) << 4;
    *(bf16x8*)(sWc + (be ^ sw)) = vh;
    *(bf16x8*)(sWc + ((be + 65536) ^ sw)) = vl;
  }
  __syncthreads();

  int bp = lane & 15;            // frag row/col within 16
  int bk = (lane >> 4) << 3;     // frag k offset
  int bswz = (bp & 7) << 4;
  int rbase = row0 + ((lane >> 4) << 2);
  int e = lane & 3;

  float creg[2][4] = {};
  float xgv[2][4];
  #pragma unroll
  for (int ni = 0; ni < 2; ++ni)
    #pragma unroll
    for (int j = 0; j < 4; ++j)
      xgv[ni][j] = (float)Xg[(size_t)(rbase + j)*G4c + pc0 + ni*16 + bp];

  #pragma unroll 1
  for (int s = 0; s < NSTEP; ++s) {
    const bf16* hrh = hCh + (size_t)s*Bc*Hc;
    const bf16* hrl = hCl + (size_t)s*Bc*Hc;
    bf16* hwh = hCh + (size_t)(s+1)*Bc*Hc;
    bf16* hwl = hCl + (size_t)(s+1)*Bc*Hc;

    f32x4 aHH[2], aHL[2], aLH[2];
    #pragma unroll
    for (int ni = 0; ni < 2; ++ni) {
      #pragma unroll
      for (int j = 0; j < 4; ++j) aHH[ni][j] = xgv[ni][j];
      aHL[ni] = (f32x4){0.f,0.f,0.f,0.f};
      aLH[ni] = (f32x4){0.f,0.f,0.f,0.f};
    }

    const bf16* pah = hrh + (size_t)(row0 + bp)*Hc + bk;
    const bf16* pal = hrl + (size_t)(row0 + bp)*Hc + bk;

    #pragma unroll
    for (int ks = 0; ks < 32; ++ks) {
      bf16x8 avh = *(const bf16x8*)(pah + ks*32);   // normal cached load
      bf16x8 avl = *(const bf16x8*)(pal + ks*32);
      #pragma unroll
      for (int ni = 0; ni < 2; ++ni) {
        int be = ((ni*16 + bp)*Hc + ks*32 + bk)*2;
        bf16x8 bvh = *(const bf16x8*)(sWc + (be ^ bswz));
        bf16x8 bvl = *(const bf16x8*)(sWc + ((be + 65536) ^ bswz));
        aHH[ni] = MFMA_B16(avh, bvh, aHH[ni]);
        aHL[ni] = MFMA_B16(avh, bvl, aHL[ni]);
        aLH[ni] = MFMA_B16(avl, bvh, aLH[ni]);
      }
    }

    // ---- LSTM epilogue: combine 4 gates across lane-quads ----
    #pragma unroll
    for (int ni = 0; ni < 2; ++ni) {
      int pcol = pc0 + ni*16 + bp;
      int hcol = pcol >> 2;
      #pragma unroll
      for (int j = 0; j < 4; ++j) {
        int rr = rbase + j;
        float v = aHH[ni][j] + aHL[ni][j] + aLH[ni][j];
        float a  = v;
        float b1 = __shfl_xor(v, 1);
        float c2 = __shfl_xor(v, 2);
        float d3 = __shfl_xor(v, 3);
        int m;
        m = e;     float gI = (m==0)?a:(m==1)?b1:(m==2)?c2:d3;
        m = e ^ 1; float gF = (m==0)?a:(m==1)?b1:(m==2)?c2:d3;
        m = e ^ 2; float gG = (m==0)?a:(m==1)?b1:(m==2)?c2:d3;
        m = e ^ 3; float gO = (m==0)?a:(m==1)?b1:(m==2)?c2:d3;

        float co = creg[ni][j];
        float cn = fsigm(gF)*co + fsigm(gI)*ftanh(gG);
        float hn = fsigm(gO)*ftanh(cn);
        creg[ni][j] = cn;
        bf16 hhi = (bf16)hn;
        bf16 hlo = (bf16)(hn - (float)hhi);
        size_t oi = (size_t)rr*Hc + hcol;
        if (e == 1) ast2(&hwh[oi], hhi);
        else if (e == 2) ast2(&hwl[oi], hlo);
        if (s > 0) {
          size_t ho = (size_t)((s-1)*Bc + rr)*Hc + hcol;
          if (e == 0) Hh[ho] = hhi;
          else if (e == 3) Hl[ho] = hlo;
        }
      }
    }

    // prefetch next step's Xg before the barrier (independent of h)
    if (s + 1 < NSTEP) {
      #pragma unroll
      for (int ni = 0; ni < 2; ++ni)
        #pragma unroll
        for (int j = 0; j < 4; ++j)
          xgv[ni][j] = (float)Xg[(size_t)((s+1)*Bc + rbase + j)*G4c + pc0 + ni*16 + bp];
    }

    if (s < NSTEP - 1) gridbar(mycnt, (s + 1) * 128);
  }
}

// ---------------- launch ----------------

extern "C" void kernel_launch(void* const* d_in, const int* in_sizes, int n_in,
                              void* d_out, int out_size, void* d_ws, size_t ws_size,
                              hipStream_t stream)
{
  const float* enc   = (const float*)d_in[0];
  const int*   gt    = (const int*)  d_in[1];
  const int*   lens  = (const int*)  d_in[2];
  const float* emb   = (const float*)d_in[3];
  const float* Winit = (const float*)d_in[4];
  const float* binit = (const float*)d_in[5];
  const float* gam   = (const float*)d_in[6];
  const float* bet   = (const float*)d_in[7];
  const float* Wih   = (const float*)d_in[8];
  const float* bih   = (const float*)d_in[9];
  const float* Whh   = (const float*)d_in[10];
  const float* bhh   = (const float*)d_in[11];
  const float* Wfc   = (const float*)d_in[12];
  const float* bfc   = (const float*)d_in[13];
  float* out = (float*)d_out;

  char* ws = (char*)d_ws;
  size_t off = 0;
  auto alloc = [&](size_t bytes) -> char* {
    char* p = ws + off;
    off += (bytes + 255) & ~(size_t)255;
    return p;
  };

  bf16* featB  = (bf16*)alloc((size_t)Bc*Fc*2);
  bf16* WinitB = (bf16*)alloc((size_t)Ec*Fc*2);
  bf16* WihpB  = (bf16*)alloc((size_t)G4c*Ec*2);
  bf16* WhhHi  = (bf16*)alloc((size_t)G4c*Hc*2);
  bf16* WhhLo  = (bf16*)alloc((size_t)G4c*Hc*2);
  bf16* WfcHi  = (bf16*)alloc((size_t)Vc*Hc*2);
  bf16* WfcLo  = (bf16*)alloc((size_t)Vc*Hc*2);
  float* bcomb = (float*)alloc((size_t)G4c*4);
  bf16* Xall   = (bf16*)alloc((size_t)MALLc*Ec*2);
  bf16* Xg     = (bf16*)alloc((size_t)MALLc*G4c*2);
  bf16* hChH   = (bf16*)alloc((size_t)(NSTEP+1)*Bc*Hc*2);  // 32-slot chain
  bf16* hChL   = (bf16*)alloc((size_t)(NSTEP+1)*Bc*Hc*2);
  bf16* HallH  = (bf16*)alloc((size_t)MOUTc*Hc*2);
  bf16* HallL  = (bf16*)alloc((size_t)MOUTc*Hc*2);
  int*  meta   = (int*) alloc((size_t)(1 + MOUTc)*4);
  int*  cnt    = (int*) alloc((size_t)128*4);

  if (off > ws_size) return;

  // zero initial state + barrier counters (captured in graph -> re-done every replay)
  hipMemsetAsync(hChH, 0, (size_t)Bc*Hc*2, stream);
  hipMemsetAsync(hChL, 0, (size_t)Bc*Hc*2, stream);
  hipMemsetAsync(cnt, 0, (size_t)128*4, stream);

  // prep
  mean_kernel<<<256, 256, 0, stream>>>(enc, featB);
  conv_kernel<<<(Ec*Fc/4 + 255)/256, 256, 0, stream>>>(Winit, WinitB, Ec*Fc/4);
  permconv_ih<<<(G4c*Ec/4 + 255)/256, 256, 0, stream>>>(Wih, WihpB);
  permsplit_hh<<<(G4c*Hc/4 + 255)/256, 256, 0, stream>>>(Whh, WhhHi, WhhLo);
  split_kernel<<<(Vc*Hc/4 + 255)/256, 256, 0, stream>>>(Wfc, WfcHi, WfcLo, Vc*Hc/4);
  bcomb_kernel<<<(G4c + 255)/256, 256, 0, stream>>>(bih, bhh, bcomb);
  gather_kernel<<<(MOUTc*(Ec/4) + 255)/256, 256, 0, stream>>>(emb, gt, Xall);
  build_ridx<<<(MOUTc + 255)/256, 256, 0, stream>>>(lens, meta);
  zerofill<<<(MOUTc*2500 + 255)/256, 256, 0, stream>>>(lens, out);

  // GEMM A: x0 = sigmoid(feat @ Winit^T + b) * BN -> X_all rows 0..127
  gemm_kernel<0,false,false><<<4, 256, 0, stream>>>(
      featB, nullptr, WinitB, nullptr, Bc, Ec, Fc, 1,
      binit, gam, bet, Xall, nullptr, nullptr);

  // GEMM C: Xg = X_all @ Wihp^T + bcomb   (3968 x 4096, K=512), nt-major + XCD swizzle
  gemm_kernel<1,false,true><<<31*32, 256, 0, stream>>>(
      Xall, nullptr, WihpB, nullptr, MALLc, G4c, Ec, 31,
      bcomb, nullptr, nullptr, Xg, nullptr, nullptr);

  // recurrence: one persistent kernel, 31 steps
  hipFuncSetAttribute(reinterpret_cast<const void*>(lstm_persist),
                      hipFuncAttributeMaxDynamicSharedMemorySize, 131072);
  lstm_persist<<<NBLK, 256, 131072, stream>>>(
      WhhHi, WhhLo, Xg, hChH, hChL, HallH, HallL, cnt);

  // GEMM E: preds = Hall[compacted] @ Wfc^T + b_fc -> scatter to out (split-3 + XCD swizzle)
  gemm_kernel<2,true,true><<<79*30, 256, 0, stream>>>(
      HallH, HallL, WfcHi, WfcLo, MOUTc, Vc, Hc, 30,
      bfc, nullptr, nullptr, nullptr, out, meta);
}